// Round 7
// baseline (569.642 us; speedup 1.0000x reference)
//
#include <hip/hip_runtime.h>
#include <math.h>

// BS=128, L=256, D=512, H=2, DK=256.
// Conv branches dead (gather idx < 256). Split-bf16 (hi/lo) MFMA GEMMs.
// A = Fq(Q(x)) via composed weight; V GEMM removed via x=(p@cap)@Wv^T+bv.
// KA GEMM: 256^2 tile, 4-slot LDS ring, counted vmcnt, T2 XOR swizzle.
// G / kg GEMMs: barrier-free tall-skinny (B-hi in LDS, B-lo via L1,
// A direct global->reg), kg reduces scores fully in-wave.

typedef short bf16x8 __attribute__((ext_vector_type(8)));
typedef float f32x4 __attribute__((ext_vector_type(4)));
typedef short short4v __attribute__((ext_vector_type(4)));

__device__ __forceinline__ short f2bf(float x) {
    union { float f; unsigned u; } c; c.f = x;
    unsigned r = c.u + 0x7FFFu + ((c.u >> 16) & 1u);
    return (short)(r >> 16);
}
__device__ __forceinline__ float bf2f(short h) {
    union { float f; unsigned u; } c; c.u = ((unsigned)(unsigned short)h) << 16;
    return c.f;
}
__device__ __forceinline__ void glds16(const void* g, void* l) {
    __builtin_amdgcn_global_load_lds(
        (const __attribute__((address_space(1))) void*)g,
        (__attribute__((address_space(3))) void*)l, 16, 0, 0);
}

// ---------------- split fp32 -> bf16 hi/lo ----------------
struct SplitArgs {
    const float* src[4];
    short* hi[4];
    short* lo[4];
    int n4[4];
};
__global__ __launch_bounds__(256) void split_multi(SplitArgs a)
{
    const int j = blockIdx.y;
    const float4* s = (const float4*)a.src[j];
    short* hi = a.hi[j];
    short* lo = a.lo[j];
    const int n4 = a.n4[j];
    for (int i = blockIdx.x * 256 + threadIdx.x; i < n4; i += gridDim.x * 256) {
        float4 x = s[i];
        short4v h, l;
        h.x = f2bf(x.x); l.x = f2bf(x.x - bf2f(h.x));
        h.y = f2bf(x.y); l.y = f2bf(x.y - bf2f(h.y));
        h.z = f2bf(x.z); l.z = f2bf(x.z - bf2f(h.z));
        h.w = f2bf(x.w); l.w = f2bf(x.w - bf2f(h.w));
        *(short4v*)&hi[i * 4] = h;
        *(short4v*)&lo[i * 4] = l;
    }
}

// ---------------- composed weight Wa = Wfq @ Wq_h, ba = Wfq@bq_h + bfq ----------------
__global__ __launch_bounds__(256)
void compose(const float* __restrict__ Wq, const float* __restrict__ bq,
             const float* __restrict__ Wfq, const float* __restrict__ bfq,
             short* __restrict__ WBhi, short* __restrict__ WBlo, float* __restrict__ ba)
{
    __shared__ float fq[256];
    __shared__ float redc[256];
    const int op = blockIdx.x;          // 0..511: h = op>>8, o = op&255
    const int h = op >> 8, o = op & 255;
    const int t = threadIdx.x;
    fq[t] = Wfq[o * 256 + t];
    redc[t] = fq[t] * bq[h * 256 + t];
    __syncthreads();
    for (int s = 128; s > 0; s >>= 1) {
        if (t < s) redc[t] += redc[t + s];
        __syncthreads();
    }
    if (t == 0) ba[op] = redc[0] + bfq[o];
    float s0 = 0.f, s1 = 0.f;
    for (int d = 0; d < 256; ++d) {
        const float f = fq[d];
        const float* wr = Wq + (size_t)(h * 256 + d) * 512;
        s0 += f * wr[t];
        s1 += f * wr[t + 256];
    }
    const size_t ro = (size_t)(512 + op) * 512;
    short h0 = f2bf(s0);
    WBhi[ro + t] = h0; WBlo[ro + t] = f2bf(s0 - bf2f(h0));
    short h1 = f2bf(s1);
    WBhi[ro + 256 + t] = h1; WBlo[ro + 256 + t] = f2bf(s1 - bf2f(h1));
}

// ---------------- KA GEMM: 256x256 tile, 4-slot ring, counted vmcnt, T2 swizzle ----------------
__global__ __launch_bounds__(512, 2)
void gemm_ka256(const short* __restrict__ Ahi, const short* __restrict__ Alo,
                const short* __restrict__ Bhi, const short* __restrict__ Blo,
                const float* __restrict__ bias1, const float* __restrict__ bias2,
                short* __restrict__ Chi, short* __restrict__ Clo)
{
    __shared__ short lds[4][16384];
    const int tid = threadIdx.x;
    int bid = blockIdx.y * 4 + blockIdx.x;       // 512 blocks
    bid = (bid & 7) * 64 + (bid >> 3);           // XCD swizzle (512 % 8 == 0)
    const int bm = (bid >> 2) * 256;
    const int bn = (bid & 3) * 256;
    const int lane = tid & 63;
    const int wv = tid >> 6;
    const int wm = wv >> 2, wn = wv & 3;
    const int fr = lane & 15, kc = lane >> 4;
    const int srow = tid >> 2;
    const int se = (((tid & 3) ^ ((srow >> 1) & 3))) * 8;

    auto stage = [&](int vk) {
        const int ph = vk % 3;
        const int k0 = (vk / 3) * 32;
        const short* Ap = (ph == 1) ? Alo : Ahi;
        const short* Bp = (ph == 2) ? Blo : Bhi;
        short* s = (short*)lds[vk & 3];
        glds16(Ap + (size_t)(bm + srow) * 512 + k0 + se,       s + tid * 8);
        glds16(Ap + (size_t)(bm + srow + 128) * 512 + k0 + se, s + (tid + 512) * 8);
        glds16(Bp + (size_t)(bn + srow) * 512 + k0 + se,       s + 8192 + tid * 8);
        glds16(Bp + (size_t)(bn + srow + 128) * 512 + k0 + se, s + 8192 + (tid + 512) * 8);
    };

    f32x4 acc[8][4];
#pragma unroll
    for (int i = 0; i < 8; ++i)
#pragma unroll
        for (int j = 0; j < 4; ++j) acc[i][j] = (f32x4){0.f, 0.f, 0.f, 0.f};

    stage(0); stage(1); stage(2);
    asm volatile("s_waitcnt vmcnt(8)" ::: "memory");
    __builtin_amdgcn_s_barrier();
    asm volatile("" ::: "memory");

    const int rsw = (fr >> 1) & 3;
    const int kce = (kc ^ rsw) * 8;

    for (int vk = 0; vk < 48; ++vk) {
        const short* s = (const short*)lds[vk & 3];
        bf16x8 af[8], bfv[4];
#pragma unroll
        for (int i = 0; i < 8; ++i)
            af[i] = *(const bf16x8*)&s[(wm * 128 + i * 16 + fr) * 32 + kce];
#pragma unroll
        for (int i = 0; i < 4; ++i)
            bfv[i] = *(const bf16x8*)&s[8192 + (wn * 64 + i * 16 + fr) * 32 + kce];
        if (vk < 45) stage(vk + 3);
        __builtin_amdgcn_s_setprio(1);
#pragma unroll
        for (int mi = 0; mi < 8; ++mi)
#pragma unroll
            for (int ni = 0; ni < 4; ++ni)
                acc[mi][ni] = __builtin_amdgcn_mfma_f32_16x16x32_bf16(af[mi], bfv[ni], acc[mi][ni], 0, 0, 0);
        __builtin_amdgcn_s_setprio(0);
        if (vk < 45)       asm volatile("s_waitcnt vmcnt(8)" ::: "memory");
        else if (vk == 45) asm volatile("s_waitcnt vmcnt(4)" ::: "memory");
        else if (vk == 46) asm volatile("s_waitcnt vmcnt(0)" ::: "memory");
        __builtin_amdgcn_s_barrier();
        asm volatile("" ::: "memory");
    }

    const int colb = bn + wn * 64;
#pragma unroll
    for (int mi = 0; mi < 8; ++mi) {
#pragma unroll
        for (int ni = 0; ni < 4; ++ni) {
#pragma unroll
            for (int r = 0; r < 4; ++r) {
                const int row = bm + wm * 128 + mi * 16 + kc * 4 + r;
                const int col = colb + ni * 16 + fr;
                const float bb = (col < 512) ? bias1[col] : bias2[col - 512];
                const float v = acc[mi][ni][r] + bb;
                const size_t off = (size_t)row * 1024 + col;
                short h = f2bf(v);
                Chi[off] = h;
                Clo[off] = f2bf(v - bf2f(h));
            }
        }
    }
}

// ---------------- G GEMM: barrier-free tall-skinny ----------------
// block (z, strip): rows strip*256..+256, cols z*256..+256 of G
// G = (K @ Wfk^T + bfk) * A ; A-operand K direct from global, Wfk-hi in LDS,
// Wfk-lo fragments via L1. 3 split products: ahi*bhi + alo*bhi + ahi*blo.
__global__ __launch_bounds__(512)
void gemm_g(const short* __restrict__ KAhi, const short* __restrict__ KAlo,
            const short* __restrict__ WHi, const short* __restrict__ WLo,
            const float* __restrict__ bias,
            short* __restrict__ Ghi, short* __restrict__ Glo)
{
    __shared__ short Bl[65536];     // Wfk-hi [256 c][256 d], chunk-swizzled
    const int t = threadIdx.x;
    const int z = blockIdx.x;
    const int strip = blockIdx.y;
    for (int i = t; i < 8192; i += 512) {
        const int c = i >> 5, ch = i & 31;
        *(bf16x8*)&Bl[c * 256 + (ch ^ (c & 7)) * 8] =
            *(const bf16x8*)&WHi[c * 256 + ch * 8];
    }
    __syncthreads();

    const int lane = t & 63, wv = t >> 6;
    const int fr = lane & 15, kc = lane >> 4;
    const int rbase = strip * 256 + wv * 32;
    const short* Ah = KAhi + z * 256;
    const short* Al = KAlo + z * 256;

    f32x4 acc[2][16];
#pragma unroll
    for (int i = 0; i < 2; ++i)
#pragma unroll
        for (int j = 0; j < 16; ++j) acc[i][j] = (f32x4){0.f, 0.f, 0.f, 0.f};

#pragma unroll
    for (int kk = 0; kk < 8; ++kk) {
        const int ko = kk * 32 + kc * 8;
        bf16x8 ah0 = *(const bf16x8*)&Ah[(size_t)(rbase + fr) * 1024 + ko];
        bf16x8 ah1 = *(const bf16x8*)&Ah[(size_t)(rbase + 16 + fr) * 1024 + ko];
        bf16x8 al0 = *(const bf16x8*)&Al[(size_t)(rbase + fr) * 1024 + ko];
        bf16x8 al1 = *(const bf16x8*)&Al[(size_t)(rbase + 16 + fr) * 1024 + ko];
#pragma unroll
        for (int nf = 0; nf < 16; ++nf) {
            const int cl = nf * 16 + fr;
            bf16x8 bh = *(const bf16x8*)&Bl[cl * 256 + ((kk * 4 + kc) ^ (fr & 7)) * 8];
            bf16x8 bl = *(const bf16x8*)&WLo[(size_t)cl * 256 + ko];
            acc[0][nf] = __builtin_amdgcn_mfma_f32_16x16x32_bf16(ah0, bh, acc[0][nf], 0, 0, 0);
            acc[1][nf] = __builtin_amdgcn_mfma_f32_16x16x32_bf16(ah1, bh, acc[1][nf], 0, 0, 0);
            acc[0][nf] = __builtin_amdgcn_mfma_f32_16x16x32_bf16(al0, bh, acc[0][nf], 0, 0, 0);
            acc[1][nf] = __builtin_amdgcn_mfma_f32_16x16x32_bf16(al1, bh, acc[1][nf], 0, 0, 0);
            acc[0][nf] = __builtin_amdgcn_mfma_f32_16x16x32_bf16(ah0, bl, acc[0][nf], 0, 0, 0);
            acc[1][nf] = __builtin_amdgcn_mfma_f32_16x16x32_bf16(ah1, bl, acc[1][nf], 0, 0, 0);
        }
    }

#pragma unroll
    for (int mf = 0; mf < 2; ++mf) {
#pragma unroll
        for (int nf = 0; nf < 16; ++nf) {
#pragma unroll
            for (int r = 0; r < 4; ++r) {
                const int row = rbase + mf * 16 + kc * 4 + r;
                const int cl = nf * 16 + fr;
                const int cg = z * 256 + cl;
                const float lin = acc[mf][nf][r] + bias[cl];
                const float av = bf2f(KAhi[(size_t)row * 1024 + 512 + cg])
                               + bf2f(KAlo[(size_t)row * 1024 + 512 + cg]);
                const float g = lin * av;
                short h = f2bf(g);
                Ghi[(size_t)row * 512 + cg] = h;
                Glo[(size_t)row * 512 + cg] = f2bf(g - bf2f(h));
            }
        }
    }
}

// ---------------- kg GEMM + fused score partials: barrier-free tall-skinny ----------------
// kg[j,c] = sigmoid(G @ Wfg2^T + bfg2) * K[j,c]; score[b,z,j] = sum_c kg*qg.
// Full N=256 per wave -> column reduce completes in-wave; one scorep slot.
__global__ __launch_bounds__(512)
void gemm_kg(const short* __restrict__ Ghi_, const short* __restrict__ Glo_,
             const short* __restrict__ KAhi, const short* __restrict__ KAlo,
             const short* __restrict__ WHi, const short* __restrict__ WLo,
             const float* __restrict__ bias,
             const float* __restrict__ qg, float* __restrict__ scorep)
{
    __shared__ short Bl[65536];     // Wfg2-hi, chunk-swizzled
    const int t = threadIdx.x;
    const int z = blockIdx.x;
    const int strip = blockIdx.y;
    for (int i = t; i < 8192; i += 512) {
        const int c = i >> 5, ch = i & 31;
        *(bf16x8*)&Bl[c * 256 + (ch ^ (c & 7)) * 8] =
            *(const bf16x8*)&WHi[c * 256 + ch * 8];
    }
    __syncthreads();

    const int lane = t & 63, wv = t >> 6;
    const int fr = lane & 15, kc = lane >> 4;
    const int rbase = strip * 256 + wv * 32;
    const short* Ah = Ghi_ + z * 256;
    const short* Al = Glo_ + z * 256;

    f32x4 acc[2][16];
#pragma unroll
    for (int i = 0; i < 2; ++i)
#pragma unroll
        for (int j = 0; j < 16; ++j) acc[i][j] = (f32x4){0.f, 0.f, 0.f, 0.f};

#pragma unroll
    for (int kk = 0; kk < 8; ++kk) {
        const int ko = kk * 32 + kc * 8;
        bf16x8 ah0 = *(const bf16x8*)&Ah[(size_t)(rbase + fr) * 512 + ko];
        bf16x8 ah1 = *(const bf16x8*)&Ah[(size_t)(rbase + 16 + fr) * 512 + ko];
        bf16x8 al0 = *(const bf16x8*)&Al[(size_t)(rbase + fr) * 512 + ko];
        bf16x8 al1 = *(const bf16x8*)&Al[(size_t)(rbase + 16 + fr) * 512 + ko];
#pragma unroll
        for (int nf = 0; nf < 16; ++nf) {
            const int cl = nf * 16 + fr;
            bf16x8 bh = *(const bf16x8*)&Bl[cl * 256 + ((kk * 4 + kc) ^ (fr & 7)) * 8];
            bf16x8 bl = *(const bf16x8*)&WLo[(size_t)cl * 256 + ko];
            acc[0][nf] = __builtin_amdgcn_mfma_f32_16x16x32_bf16(ah0, bh, acc[0][nf], 0, 0, 0);
            acc[1][nf] = __builtin_amdgcn_mfma_f32_16x16x32_bf16(ah1, bh, acc[1][nf], 0, 0, 0);
            acc[0][nf] = __builtin_amdgcn_mfma_f32_16x16x32_bf16(al0, bh, acc[0][nf], 0, 0, 0);
            acc[1][nf] = __builtin_amdgcn_mfma_f32_16x16x32_bf16(al1, bh, acc[1][nf], 0, 0, 0);
            acc[0][nf] = __builtin_amdgcn_mfma_f32_16x16x32_bf16(ah0, bl, acc[0][nf], 0, 0, 0);
            acc[1][nf] = __builtin_amdgcn_mfma_f32_16x16x32_bf16(ah1, bl, acc[1][nf], 0, 0, 0);
        }
    }

    float pt[2][4];
#pragma unroll
    for (int mf = 0; mf < 2; ++mf)
#pragma unroll
        for (int r = 0; r < 4; ++r) pt[mf][r] = 0.f;

#pragma unroll
    for (int nf = 0; nf < 16; ++nf) {
        const int cl = nf * 16 + fr;
        const int cg = z * 256 + cl;
        const float qgv = qg[strip * 512 + cg];
        const float bb = bias[cl];
#pragma unroll
        for (int mf = 0; mf < 2; ++mf) {
#pragma unroll
            for (int r = 0; r < 4; ++r) {
                const int row = rbase + mf * 16 + kc * 4 + r;
                const float v = acc[mf][nf][r] + bb;
                const float e = bf2f(KAhi[(size_t)row * 1024 + cg])
                              + bf2f(KAlo[(size_t)row * 1024 + cg]);
                const float kgv = e / (1.f + expf(-v));
                pt[mf][r] += kgv * qgv;
            }
        }
    }

#pragma unroll
    for (int mf = 0; mf < 2; ++mf) {
#pragma unroll
        for (int r = 0; r < 4; ++r) {
            float p = pt[mf][r];
            p += __shfl_xor(p, 1);
            p += __shfl_xor(p, 2);
            p += __shfl_xor(p, 4);
            p += __shfl_xor(p, 8);
            if (fr == 0) {
                const int j = wv * 32 + mf * 16 + kc * 4 + r;
                scorep[(size_t)(strip * 2 + z) * 256 + j] = p;
            }
        }
    }
}

// ---------------- qg at gathered rows: Q fp32-exact from cap ----------------
__global__ __launch_bounds__(256)
void qg_kernel(const float* __restrict__ cap,
               const short* __restrict__ Ghi, const short* __restrict__ Glo,
               const float* __restrict__ Wq, const float* __restrict__ bq,
               const float* __restrict__ Wfg, const float* __restrict__ bfg,
               const int* __restrict__ lengths, float* __restrict__ qg)
{
    __shared__ float cr[512];
    __shared__ float gs[256];
    const int b = blockIdx.x >> 1, h = blockIdx.x & 1;
    const int t = threadIdx.x;
    int r = lengths[b] - 1;
    if (r < 0) r = 0;
    if (r > 255) r = 255;
    const size_t base = ((size_t)b * 256 + r) * 512;
    cr[t] = cap[base + t];
    cr[t + 256] = cap[base + 256 + t];
    gs[t] = bf2f(Ghi[base + h * 256 + t]) + bf2f(Glo[base + h * 256 + t]);
    __syncthreads();
    const float4* wq4 = (const float4*)(Wq + (size_t)(h * 256 + t) * 512);
    float q = 0.f;
    for (int k4 = 0; k4 < 128; ++k4) {
        float4 w = wq4[k4];
        q += w.x * cr[k4 * 4 + 0] + w.y * cr[k4 * 4 + 1]
           + w.z * cr[k4 * 4 + 2] + w.w * cr[k4 * 4 + 3];
    }
    q += bq[h * 256 + t];
    const float4* w4 = (const float4*)(Wfg + (size_t)t * 256);
    float a = 0.f;
    for (int k4 = 0; k4 < 64; ++k4) {
        float4 w = w4[k4];
        a += w.x * gs[k4 * 4 + 0] + w.y * gs[k4 * 4 + 1]
           + w.z * gs[k4 * 4 + 2] + w.w * gs[k4 * 4 + 3];
    }
    a += bfg[t];
    qg[b * 512 + h * 256 + t] = q / (1.f + expf(-a));
}

// ---------------- softmax (inline) + pbar[b][h][c] = sum_j p[h][j]*cap[b,j,c] ----------------
__global__ __launch_bounds__(256)
void pbar_kernel(const float* __restrict__ scorep, const float* __restrict__ cap,
                 float* __restrict__ pbar)
{
    __shared__ float sc[512], red[512];
    const int b = blockIdx.y, cgp = blockIdx.x;
    const int t = threadIdx.x;
#pragma unroll
    for (int i = 0; i < 2; ++i) {
        const int o = t + i * 256;
        sc[o] = floorf(scorep[(size_t)b * 512 + o] * 0.0625f);
    }
    __syncthreads();
    red[t] = sc[t]; red[t + 256] = sc[t + 256];
    __syncthreads();
    for (int s = 128; s > 0; s >>= 1) {
        if (t < s) {
            red[t] = fmaxf(red[t], red[t + s]);
            red[256 + t] = fmaxf(red[256 + t], red[256 + t + s]);
        }
        __syncthreads();
    }
    const float mx0 = red[0], mx1 = red[256];
    __syncthreads();
    const float e0 = expf(sc[t] - mx0);
    const float e1 = expf(sc[t + 256] - mx1);
    red[t] = e0; red[t + 256] = e1;
    __syncthreads();
    for (int s = 128; s > 0; s >>= 1) {
        if (t < s) { red[t] += red[t + s]; red[256 + t] += red[256 + t + s]; }
        __syncthreads();
    }
    sc[t] = e0 / red[0];
    sc[t + 256] = e1 / red[256];
    __syncthreads();

    const int c = cgp * 64 + (t & 63);
    const int jg = t >> 6;
    float a0 = 0.f, a1 = 0.f;
    for (int j = jg * 64; j < jg * 64 + 64; ++j) {
        const float cv = cap[((size_t)(b * 256 + j)) * 512 + c];
        a0 += sc[j] * cv;
        a1 += sc[256 + j] * cv;
    }
    red[t] = a0;
    __syncthreads();
    if (t < 64) {
        const float s0 = red[t] + red[t + 64] + red[t + 128] + red[t + 192];
        pbar[b * 1024 + cgp * 64 + t] = s0;
    }
    __syncthreads();
    red[t] = a1;
    __syncthreads();
    if (t < 64) {
        const float s1 = red[t] + red[t + 64] + red[t + 128] + red[t + 192];
        pbar[b * 1024 + 512 + cgp * 64 + t] = s1;
    }
}

// ---------------- x = pbar@Wv^T + bv, BN1, residual ----------------
__global__ __launch_bounds__(256)
void bnx_kernel(const float* __restrict__ pbar, const float* __restrict__ cap,
                const int* __restrict__ lengths,
                const float* __restrict__ Wv, const float* __restrict__ bv,
                const float* __restrict__ g1, const float* __restrict__ b1,
                const float* __restrict__ m1, const float* __restrict__ v1,
                float* __restrict__ xga)
{
    __shared__ float pb[1024];
    const int b = blockIdx.x;
    const int t = threadIdx.x;
    int r = lengths[b] - 1;
    if (r < 0) r = 0;
    if (r > 255) r = 255;
    const size_t base = ((size_t)b * 256 + r) * 512;
    pb[t] = pbar[b * 1024 + t];
    pb[t + 256] = pbar[b * 1024 + 256 + t];
    pb[t + 512] = pbar[b * 1024 + 512 + t];
    pb[t + 768] = pbar[b * 1024 + 768 + t];
    __syncthreads();
    float x0 = 0.f, x1 = 0.f;
    {
        const float4* w4 = (const float4*)(Wv + (size_t)t * 512);
        for (int k4 = 0; k4 < 128; ++k4) {
            float4 w = w4[k4];
            x0 += w.x * pb[k4 * 4 + 0] + w.y * pb[k4 * 4 + 1]
                + w.z * pb[k4 * 4 + 2] + w.w * pb[k4 * 4 + 3];
        }
        x0 += bv[t];
    }
    {
        const float4* w4 = (const float4*)(Wv + (size_t)(t + 256) * 512);
        for (int k4 = 0; k4 < 128; ++k4) {
            float4 w = w4[k4];
            x1 += w.x * pb[512 + k4 * 4 + 0] + w.y * pb[512 + k4 * 4 + 1]
                + w.z * pb[512 + k4 * 4 + 2] + w.w * pb[512 + k4 * 4 + 3];
        }
        x1 += bv[t + 256];
    }
    const int c0 = t, c1 = t + 256;
    const float s0 = g1[c0] / sqrtf(v1[c0] + 1e-5f);
    const float s1 = g1[c1] / sqrtf(v1[c1] + 1e-5f);
    xga[b * 512 + c0] = cap[base + c0] + (x0 - m1[c0]) * s0 + b1[c0];
    xga[b * 512 + c1] = cap[base + c1] + (x1 - m1[c1]) * s1 + b1[c1];
}

// ---------------- MLP strip GEMMs (weights read once) ----------------
__global__ __launch_bounds__(256)
void mlp1(const float* __restrict__ xga, const float* __restrict__ W,
          const float* __restrict__ bias, float* __restrict__ hid)
{
    __shared__ float xs[16 * 512];
    const int r0 = blockIdx.y * 16;
    const int c0 = blockIdx.x * 64;
    for (int i = threadIdx.x; i < 2048; i += 256)
        ((float4*)xs)[i] = ((const float4*)(xga + (size_t)r0 * 512))[i];
    __syncthreads();
    const int col = c0 + (threadIdx.x & 63);
    const int rg = (threadIdx.x >> 6) * 4;
    float acc[4] = {0.f, 0.f, 0.f, 0.f};
    const float4* w4 = (const float4*)(W + (size_t)col * 512);
    for (int k4 = 0; k4 < 128; ++k4) {
        float4 w = w4[k4];
#pragma unroll
        for (int rr = 0; rr < 4; ++rr) {
            float4 x = *(const float4*)&xs[(rg + rr) * 512 + k4 * 4];
            acc[rr] += w.x * x.x + w.y * x.y + w.z * x.z + w.w * x.w;
        }
    }
    const float bb = bias[col];
#pragma unroll
    for (int rr = 0; rr < 4; ++rr)
        hid[(size_t)(r0 + rg + rr) * 1024 + col] = fmaxf(acc[rr] + bb, 0.f);
}

__global__ __launch_bounds__(256)
void mlp2(const float* __restrict__ hid, const float* __restrict__ W,
          const float* __restrict__ bias, const float* __restrict__ xga,
          float* __restrict__ tex)
{
    __shared__ float xs[16 * 1024];
    const int r0 = blockIdx.y * 16;
    const int c0 = blockIdx.x * 64;
    for (int i = threadIdx.x; i < 4096; i += 256)
        ((float4*)xs)[i] = ((const float4*)(hid + (size_t)r0 * 1024))[i];
    __syncthreads();
    const int col = c0 + (threadIdx.x & 63);
    const int rg = (threadIdx.x >> 6) * 4;
    float acc[4] = {0.f, 0.f, 0.f, 0.f};
    const float4* w4 = (const float4*)(W + (size_t)col * 1024);
    for (int k4 = 0; k4 < 256; ++k4) {
        float4 w = w4[k4];
#pragma unroll
        for (int rr = 0; rr < 4; ++rr) {
            float4 x = *(const float4*)&xs[(rg + rr) * 1024 + k4 * 4];
            acc[rr] += w.x * x.x + w.y * x.y + w.z * x.z + w.w * x.w;
        }
    }
    const float bb = bias[col];
#pragma unroll
    for (int rr = 0; rr < 4; ++rr) {
        const int row = r0 + rg + rr;
        tex[(size_t)row * 512 + col] = acc[rr] + bb + xga[(size_t)row * 512 + col];
    }
}

__global__ __launch_bounds__(256)
void norm_out(const float* __restrict__ tex, float* __restrict__ out)
{
    __shared__ float red[256];
    const int b = blockIdx.x;
    const int t = threadIdx.x;
    const float a = tex[b * 512 + t];
    const float c = tex[b * 512 + 256 + t];
    red[t] = a * a + c * c;
    __syncthreads();
    for (int s = 128; s > 0; s >>= 1) {
        if (t < s) red[t] += red[t + s];
        __syncthreads();
    }
    const float inv = 1.f / (sqrtf(red[0]) + 1e-8f);
    out[b * 512 + t] = a * inv;
    out[b * 512 + 256 + t] = c * inv;
}

extern "C" void kernel_launch(void* const* d_in, const int* in_sizes, int n_in,
                              void* d_out, int out_size, void* d_ws, size_t ws_size,
                              hipStream_t stream)
{
    const float* cap = (const float*)d_in[0];
    const int* lengths = (const int*)d_in[1];
    const float* Wq  = (const float*)d_in[2];
    const float* Wk  = (const float*)d_in[3];
    const float* Wv  = (const float*)d_in[4];
    const float* bq  = (const float*)d_in[5];
    const float* bk  = (const float*)d_in[6];
    const float* bv  = (const float*)d_in[7];
    const float* Wfq = (const float*)d_in[8];
    const float* bfq = (const float*)d_in[9];
    const float* Wfk = (const float*)d_in[10];
    const float* bfk = (const float*)d_in[11];
    const float* Wfg = (const float*)d_in[12];
    const float* bfg = (const float*)d_in[13];
    const float* g1  = (const float*)d_in[14];
    const float* b1  = (const float*)d_in[15];
    const float* m1  = (const float*)d_in[16];
    const float* v1  = (const float*)d_in[17];
    const float* Wm1 = (const float*)d_in[30];
    const float* bm1 = (const float*)d_in[31];
    const float* Wm2 = (const float*)d_in[32];
    const float* bm2 = (const float*)d_in[33];
    float* out = (float*)d_out;

    char* w = (char*)d_ws;
    const size_t MB = 1024 * 1024;
    short* capHi = (short*)(w);                // 32MB  -> Ghi after G gemm
    short* capLo = (short*)(w + 32 * MB);      // 32MB  -> Glo
    short* KAhi  = (short*)(w + 64 * MB);      // 64MB  [32768,1024]: cols 0-511 K, 512-1023 A=Fq(Q)
    short* KAlo  = (short*)(w + 128 * MB);     // 64MB
    char* wp = w + 192 * MB;
    short* WBhi  = (short*)wp; wp += 1048576;  // [1024,512]: rows 0-511 Wk, 512-1023 Wa
    short* WBlo  = (short*)wp; wp += 1048576;
    short* WfkHi = (short*)wp; wp += 131072;
    short* WfkLo = (short*)wp; wp += 131072;
    short* Wfg2Hi = (short*)wp; wp += 131072;
    short* Wfg2Lo = (short*)wp; wp += 131072;
    float* ba     = (float*)wp; wp += 2048;
    float* qg     = (float*)wp; wp += 262144;
    float* scorep = (float*)wp; wp += 262144;   // [128][2][256]
    float* pbar   = (float*)wp; wp += 524288;   // [128][2][512]
    float* xga    = (float*)wp; wp += 262144;
    float* hid    = (float*)wp; wp += 524288;
    float* tex    = (float*)wp; wp += 262144;
    short* Ghi = capHi;
    short* Glo = capLo;

    // 1. splits: cap, Wk (-> WB rows 0-511), Wfk, Wfg2
    SplitArgs sa;
    sa.src[0] = cap;          sa.hi[0] = capHi;  sa.lo[0] = capLo;  sa.n4[0] = 4194304;
    sa.src[1] = Wk;           sa.hi[1] = WBhi;   sa.lo[1] = WBlo;   sa.n4[1] = 65536;
    sa.src[2] = Wfk;          sa.hi[2] = WfkHi;  sa.lo[2] = WfkLo;  sa.n4[2] = 16384;
    sa.src[3] = Wfg + 65536;  sa.hi[3] = Wfg2Hi; sa.lo[3] = Wfg2Lo; sa.n4[3] = 16384;
    split_multi<<<dim3(4096, 4), 256, 0, stream>>>(sa);

    // 2. composed Wa -> WB rows 512-1023, ba
    compose<<<dim3(512), 256, 0, stream>>>(Wq, bq, Wfq, bfq, WBhi, WBlo, ba);

    // 3. KA fused: 256^2-tile ring kernel
    gemm_ka256<<<dim3(4, 128), 512, 0, stream>>>(capHi, capLo, WBhi, WBlo, bk, ba, KAhi, KAlo);

    // 4. G = (K_h Wfk^T + bfk) * A  -> overwrites cap splits (barrier-free)
    gemm_g<<<dim3(2, 128), 512, 0, stream>>>(KAhi, KAlo, WfkHi, WfkLo, bfk, Ghi, Glo);

    // 5. qg at gathered rows (Q fp32 from cap)
    qg_kernel<<<dim3(256), 256, 0, stream>>>(cap, Ghi, Glo, Wq, bq, Wfg, bfg, lengths, qg);

    // 6. kg gemm + fused scores (barrier-free, in-wave reduce)
    gemm_kg<<<dim3(2, 128), 512, 0, stream>>>(Ghi, Glo, KAhi, KAlo, Wfg2Hi, Wfg2Lo,
                                              bfg + 256, qg, scorep);

    // 7-8. softmax+pbar, BN/residual
    pbar_kernel<<<dim3(8, 128), 256, 0, stream>>>(scorep, cap, pbar);
    bnx_kernel<<<dim3(128), 256, 0, stream>>>(pbar, cap, lengths, Wv, bv, g1, b1, m1, v1, xga);

    // 9-11. MLP, norm
    mlp1<<<dim3(16, 8), 256, 0, stream>>>(xga, Wm1, bm1, hid);
    mlp2<<<dim3(8, 8), 256, 0, stream>>>(hid, Wm2, bm2, xga, tex);
    norm_out<<<dim3(128), 256, 0, stream>>>(tex, out);
}

// Round 8
// 493.433 us; speedup vs baseline: 1.1544x; 1.1544x over previous
//
#include <hip/hip_runtime.h>
#include <math.h>

// BS=128, L=256, D=512, H=2, DK=256.
// Conv branches dead (gather idx < 256). Split-bf16 (hi/lo) MFMA GEMMs.
// A = Fq(Q(x)) via composed weight; V GEMM removed via x=(p@cap)@Wv^T+bv.
// KA GEMM: 256^2 tile, 4-slot LDS ring, counted vmcnt, T2 XOR swizzle.
// G and kg: same ring structure on the head-reshaped [65536,256] view
// (row m = 2r+h), G's *A epilogue / kg's score-reduce fused in.

typedef short bf16x8 __attribute__((ext_vector_type(8)));
typedef float f32x4 __attribute__((ext_vector_type(4)));
typedef short short4v __attribute__((ext_vector_type(4)));

__device__ __forceinline__ short f2bf(float x) {
    union { float f; unsigned u; } c; c.f = x;
    unsigned r = c.u + 0x7FFFu + ((c.u >> 16) & 1u);
    return (short)(r >> 16);
}
__device__ __forceinline__ float bf2f(short h) {
    union { float f; unsigned u; } c; c.u = ((unsigned)(unsigned short)h) << 16;
    return c.f;
}
__device__ __forceinline__ void glds16(const void* g, void* l) {
    __builtin_amdgcn_global_load_lds(
        (const __attribute__((address_space(1))) void*)g,
        (__attribute__((address_space(3))) void*)l, 16, 0, 0);
}

// ---------------- split fp32 -> bf16 hi/lo ----------------
struct SplitArgs {
    const float* src[4];
    short* hi[4];
    short* lo[4];
    int n4[4];
};
__global__ __launch_bounds__(256) void split_multi(SplitArgs a)
{
    const int j = blockIdx.y;
    const float4* s = (const float4*)a.src[j];
    short* hi = a.hi[j];
    short* lo = a.lo[j];
    const int n4 = a.n4[j];
    for (int i = blockIdx.x * 256 + threadIdx.x; i < n4; i += gridDim.x * 256) {
        float4 x = s[i];
        short4v h, l;
        h.x = f2bf(x.x); l.x = f2bf(x.x - bf2f(h.x));
        h.y = f2bf(x.y); l.y = f2bf(x.y - bf2f(h.y));
        h.z = f2bf(x.z); l.z = f2bf(x.z - bf2f(h.z));
        h.w = f2bf(x.w); l.w = f2bf(x.w - bf2f(h.w));
        *(short4v*)&hi[i * 4] = h;
        *(short4v*)&lo[i * 4] = l;
    }
}

// ---------------- composed weight Wa = Wfq @ Wq_h, ba = Wfq@bq_h + bfq ----------------
__global__ __launch_bounds__(256)
void compose(const float* __restrict__ Wq, const float* __restrict__ bq,
             const float* __restrict__ Wfq, const float* __restrict__ bfq,
             short* __restrict__ WBhi, short* __restrict__ WBlo, float* __restrict__ ba)
{
    __shared__ float fq[256];
    __shared__ float redc[256];
    const int op = blockIdx.x;          // 0..511: h = op>>8, o = op&255
    const int h = op >> 8, o = op & 255;
    const int t = threadIdx.x;
    fq[t] = Wfq[o * 256 + t];
    redc[t] = fq[t] * bq[h * 256 + t];
    __syncthreads();
    for (int s = 128; s > 0; s >>= 1) {
        if (t < s) redc[t] += redc[t + s];
        __syncthreads();
    }
    if (t == 0) ba[op] = redc[0] + bfq[o];
    float s0 = 0.f, s1 = 0.f;
    for (int d = 0; d < 256; ++d) {
        const float f = fq[d];
        const float* wr = Wq + (size_t)(h * 256 + d) * 512;
        s0 += f * wr[t];
        s1 += f * wr[t + 256];
    }
    const size_t ro = (size_t)(512 + op) * 512;
    short h0 = f2bf(s0);
    WBhi[ro + t] = h0; WBlo[ro + t] = f2bf(s0 - bf2f(h0));
    short h1 = f2bf(s1);
    WBhi[ro + 256 + t] = h1; WBlo[ro + 256 + t] = f2bf(s1 - bf2f(h1));
}

// ---------------- KA GEMM: 256x256 tile, 4-slot ring, counted vmcnt, T2 swizzle ----------------
__global__ __launch_bounds__(512, 2)
void gemm_ka256(const short* __restrict__ Ahi, const short* __restrict__ Alo,
                const short* __restrict__ Bhi, const short* __restrict__ Blo,
                const float* __restrict__ bias1, const float* __restrict__ bias2,
                short* __restrict__ Chi, short* __restrict__ Clo)
{
    __shared__ short lds[4][16384];
    const int tid = threadIdx.x;
    int bid = blockIdx.y * 4 + blockIdx.x;       // 512 blocks
    bid = (bid & 7) * 64 + (bid >> 3);           // XCD swizzle (512 % 8 == 0)
    const int bm = (bid >> 2) * 256;
    const int bn = (bid & 3) * 256;
    const int lane = tid & 63;
    const int wv = tid >> 6;
    const int wm = wv >> 2, wn = wv & 3;
    const int fr = lane & 15, kc = lane >> 4;
    const int srow = tid >> 2;
    const int se = (((tid & 3) ^ ((srow >> 1) & 3))) * 8;

    auto stage = [&](int vk) {
        const int ph = vk % 3;
        const int k0 = (vk / 3) * 32;
        const short* Ap = (ph == 1) ? Alo : Ahi;
        const short* Bp = (ph == 2) ? Blo : Bhi;
        short* s = (short*)lds[vk & 3];
        glds16(Ap + (size_t)(bm + srow) * 512 + k0 + se,       s + tid * 8);
        glds16(Ap + (size_t)(bm + srow + 128) * 512 + k0 + se, s + (tid + 512) * 8);
        glds16(Bp + (size_t)(bn + srow) * 512 + k0 + se,       s + 8192 + tid * 8);
        glds16(Bp + (size_t)(bn + srow + 128) * 512 + k0 + se, s + 8192 + (tid + 512) * 8);
    };

    f32x4 acc[8][4];
#pragma unroll
    for (int i = 0; i < 8; ++i)
#pragma unroll
        for (int j = 0; j < 4; ++j) acc[i][j] = (f32x4){0.f, 0.f, 0.f, 0.f};

    stage(0); stage(1); stage(2);
    asm volatile("s_waitcnt vmcnt(8)" ::: "memory");
    __builtin_amdgcn_s_barrier();
    asm volatile("" ::: "memory");

    const int kce = ((kc ^ ((fr >> 1) & 3))) * 8;

    for (int vk = 0; vk < 48; ++vk) {
        const short* s = (const short*)lds[vk & 3];
        bf16x8 af[8], bfv[4];
#pragma unroll
        for (int i = 0; i < 8; ++i)
            af[i] = *(const bf16x8*)&s[(wm * 128 + i * 16 + fr) * 32 + kce];
#pragma unroll
        for (int i = 0; i < 4; ++i)
            bfv[i] = *(const bf16x8*)&s[8192 + (wn * 64 + i * 16 + fr) * 32 + kce];
        if (vk < 45) stage(vk + 3);
        __builtin_amdgcn_s_setprio(1);
#pragma unroll
        for (int mi = 0; mi < 8; ++mi)
#pragma unroll
            for (int ni = 0; ni < 4; ++ni)
                acc[mi][ni] = __builtin_amdgcn_mfma_f32_16x16x32_bf16(af[mi], bfv[ni], acc[mi][ni], 0, 0, 0);
        __builtin_amdgcn_s_setprio(0);
        if (vk < 45)       asm volatile("s_waitcnt vmcnt(8)" ::: "memory");
        else if (vk == 45) asm volatile("s_waitcnt vmcnt(4)" ::: "memory");
        else if (vk == 46) asm volatile("s_waitcnt vmcnt(0)" ::: "memory");
        __builtin_amdgcn_s_barrier();
        asm volatile("" ::: "memory");
    }

    const int colb = bn + wn * 64;
#pragma unroll
    for (int mi = 0; mi < 8; ++mi) {
#pragma unroll
        for (int ni = 0; ni < 4; ++ni) {
#pragma unroll
            for (int r = 0; r < 4; ++r) {
                const int row = bm + wm * 128 + mi * 16 + kc * 4 + r;
                const int col = colb + ni * 16 + fr;
                const float bb = (col < 512) ? bias1[col] : bias2[col - 512];
                const float v = acc[mi][ni][r] + bb;
                const size_t off = (size_t)row * 1024 + col;
                short h = f2bf(v);
                Chi[off] = h;
                Clo[off] = f2bf(v - bf2f(h));
            }
        }
    }
}

// ---------------- reshaped ring GEMM for G and kg ----------------
// View: rows m = 2r+h of a [65536, 256] matrix; B = per-head weight [256,256].
// MODE 0 (G):  C_m = (A_m @ Wfk^T + bfk) * Aop_m   (Aop = A-half of KA), split write
// MODE 1 (kg): score_m = sum_c sigmoid(A_m@Wfg2^T+bfg2)_c * K_m[c] * qg_(b,h)[c]
template<int MODE>
__global__ __launch_bounds__(512)
void gemm_rs(const short* __restrict__ Ahi, const short* __restrict__ Alo,
             const short* __restrict__ Bhi, const short* __restrict__ Blo,
             const float* __restrict__ bias,
             const short* __restrict__ Ehi, const short* __restrict__ Elo,
             const float* __restrict__ qg, float* __restrict__ scorep,
             short* __restrict__ Chi, short* __restrict__ Clo)
{
    __shared__ short lds[4][16384];
    __shared__ float sp[256][4];
    const int tid = threadIdx.x;
    int bid = blockIdx.x;                        // 256 blocks
    bid = (bid & 7) * 32 + (bid >> 3);           // XCD swizzle (256 % 8 == 0)
    const int bm = bid * 256;
    const int lane = tid & 63;
    const int wv = tid >> 6;
    const int wm = wv >> 2, wn = wv & 3;
    const int fr = lane & 15, kc = lane >> 4;
    const int srow = tid >> 2;
    const int se = (((tid & 3) ^ ((srow >> 1) & 3))) * 8;

    auto aoff = [&](int m) -> size_t {
        if (MODE == 0) return ((size_t)(m >> 1)) * 1024 + (m & 1) * 256;  // K in KA
        else           return (size_t)m * 256;                            // G contiguous
    };

    auto stage = [&](int vk) {
        const int ph = vk % 3;
        const int k0 = (vk / 3) * 32;
        const short* Ap = (ph == 1) ? Alo : Ahi;
        const short* Bp = (ph == 2) ? Blo : Bhi;
        short* s = (short*)lds[vk & 3];
        glds16(Ap + aoff(bm + srow) + k0 + se,            s + tid * 8);
        glds16(Ap + aoff(bm + srow + 128) + k0 + se,      s + (tid + 512) * 8);
        glds16(Bp + (size_t)srow * 256 + k0 + se,         s + 8192 + tid * 8);
        glds16(Bp + (size_t)(srow + 128) * 256 + k0 + se, s + 8192 + (tid + 512) * 8);
    };

    f32x4 acc[8][4];
#pragma unroll
    for (int i = 0; i < 8; ++i)
#pragma unroll
        for (int j = 0; j < 4; ++j) acc[i][j] = (f32x4){0.f, 0.f, 0.f, 0.f};

    stage(0); stage(1); stage(2);
    asm volatile("s_waitcnt vmcnt(8)" ::: "memory");
    __builtin_amdgcn_s_barrier();
    asm volatile("" ::: "memory");

    const int kce = ((kc ^ ((fr >> 1) & 3))) * 8;

    for (int vk = 0; vk < 24; ++vk) {
        const short* s = (const short*)lds[vk & 3];
        bf16x8 af[8], bfv[4];
#pragma unroll
        for (int i = 0; i < 8; ++i)
            af[i] = *(const bf16x8*)&s[(wm * 128 + i * 16 + fr) * 32 + kce];
#pragma unroll
        for (int i = 0; i < 4; ++i)
            bfv[i] = *(const bf16x8*)&s[8192 + (wn * 64 + i * 16 + fr) * 32 + kce];
        if (vk < 21) stage(vk + 3);
        __builtin_amdgcn_s_setprio(1);
#pragma unroll
        for (int mi = 0; mi < 8; ++mi)
#pragma unroll
            for (int ni = 0; ni < 4; ++ni)
                acc[mi][ni] = __builtin_amdgcn_mfma_f32_16x16x32_bf16(af[mi], bfv[ni], acc[mi][ni], 0, 0, 0);
        __builtin_amdgcn_s_setprio(0);
        if (vk < 21)       asm volatile("s_waitcnt vmcnt(8)" ::: "memory");
        else if (vk == 21) asm volatile("s_waitcnt vmcnt(4)" ::: "memory");
        else if (vk == 22) asm volatile("s_waitcnt vmcnt(0)" ::: "memory");
        __builtin_amdgcn_s_barrier();
        asm volatile("" ::: "memory");
    }

    if (MODE == 0) {
#pragma unroll
        for (int mi = 0; mi < 8; ++mi) {
#pragma unroll
            for (int ni = 0; ni < 4; ++ni) {
#pragma unroll
                for (int r = 0; r < 4; ++r) {
                    const int m = bm + wm * 128 + mi * 16 + kc * 4 + r;
                    const int cl = wn * 64 + ni * 16 + fr;
                    const float lin = acc[mi][ni][r] + bias[cl];
                    const size_t eo = ((size_t)(m >> 1)) * 1024 + 512 + (m & 1) * 256 + cl;
                    const float e = bf2f(Ehi[eo]) + bf2f(Elo[eo]);
                    const float g = lin * e;
                    short h = f2bf(g);
                    Chi[(size_t)m * 256 + cl] = h;
                    Clo[(size_t)m * 256 + cl] = f2bf(g - bf2f(h));
                }
            }
        }
    } else {
        float pt[8][4];
#pragma unroll
        for (int mi = 0; mi < 8; ++mi)
#pragma unroll
            for (int r = 0; r < 4; ++r) pt[mi][r] = 0.f;
#pragma unroll
        for (int ni = 0; ni < 4; ++ni) {
            const int cl = wn * 64 + ni * 16 + fr;
            const float bb = bias[cl];
#pragma unroll
            for (int mi = 0; mi < 8; ++mi) {
#pragma unroll
                for (int r = 0; r < 4; ++r) {
                    const int m = bm + wm * 128 + mi * 16 + kc * 4 + r;
                    const float v = acc[mi][ni][r] + bb;
                    const size_t eo = ((size_t)(m >> 1)) * 1024 + (m & 1) * 256 + cl;
                    const float e = bf2f(Ehi[eo]) + bf2f(Elo[eo]);
                    const float kgv = e / (1.f + expf(-v));
                    pt[mi][r] += kgv * qg[(size_t)(m >> 9) * 512 + (m & 1) * 256 + cl];
                }
            }
        }
#pragma unroll
        for (int mi = 0; mi < 8; ++mi) {
#pragma unroll
            for (int r = 0; r < 4; ++r) {
                float p = pt[mi][r];
                p += __shfl_xor(p, 1);
                p += __shfl_xor(p, 2);
                p += __shfl_xor(p, 4);
                p += __shfl_xor(p, 8);
                if (fr == 0) sp[wm * 128 + mi * 16 + kc * 4 + r][wn] = p;
            }
        }
        __syncthreads();
        if (tid < 256)
            scorep[bm + tid] = sp[tid][0] + sp[tid][1] + sp[tid][2] + sp[tid][3];
    }
}

// ---------------- qg at gathered rows: Q fp32-exact from cap ----------------
__global__ __launch_bounds__(256)
void qg_kernel(const float* __restrict__ cap,
               const short* __restrict__ Ghi, const short* __restrict__ Glo,
               const float* __restrict__ Wq, const float* __restrict__ bq,
               const float* __restrict__ Wfg, const float* __restrict__ bfg,
               const int* __restrict__ lengths, float* __restrict__ qg)
{
    __shared__ float cr[512];
    __shared__ float gs[256];
    const int b = blockIdx.x >> 1, h = blockIdx.x & 1;
    const int t = threadIdx.x;
    int r = lengths[b] - 1;
    if (r < 0) r = 0;
    if (r > 255) r = 255;
    const size_t base = ((size_t)b * 256 + r) * 512;
    cr[t] = cap[base + t];
    cr[t + 256] = cap[base + 256 + t];
    gs[t] = bf2f(Ghi[base + h * 256 + t]) + bf2f(Glo[base + h * 256 + t]);
    __syncthreads();
    const float4* wq4 = (const float4*)(Wq + (size_t)(h * 256 + t) * 512);
    float q = 0.f;
    for (int k4 = 0; k4 < 128; ++k4) {
        float4 w = wq4[k4];
        q += w.x * cr[k4 * 4 + 0] + w.y * cr[k4 * 4 + 1]
           + w.z * cr[k4 * 4 + 2] + w.w * cr[k4 * 4 + 3];
    }
    q += bq[h * 256 + t];
    const float4* w4 = (const float4*)(Wfg + (size_t)t * 256);
    float a = 0.f;
    for (int k4 = 0; k4 < 64; ++k4) {
        float4 w = w4[k4];
        a += w.x * gs[k4 * 4 + 0] + w.y * gs[k4 * 4 + 1]
           + w.z * gs[k4 * 4 + 2] + w.w * gs[k4 * 4 + 3];
    }
    a += bfg[t];
    qg[b * 512 + h * 256 + t] = q / (1.f + expf(-a));
}

// ---------------- softmax (inline) + pbar[b][h][c] = sum_j p[h][j]*cap[b,j,c] ----------------
// scorep layout: [b*512 + j*2 + h]
__global__ __launch_bounds__(256)
void pbar_kernel(const float* __restrict__ scorep, const float* __restrict__ cap,
                 float* __restrict__ pbar)
{
    __shared__ float sc[512], red[512];
    const int b = blockIdx.y, cgp = blockIdx.x;
    const int t = threadIdx.x;
#pragma unroll
    for (int i = 0; i < 2; ++i) {
        const int o = t + i * 256;
        const int h = o >> 8, j = o & 255;
        sc[o] = floorf(scorep[(size_t)b * 512 + j * 2 + h] * 0.0625f);
    }
    __syncthreads();
    red[t] = sc[t]; red[t + 256] = sc[t + 256];
    __syncthreads();
    for (int s = 128; s > 0; s >>= 1) {
        if (t < s) {
            red[t] = fmaxf(red[t], red[t + s]);
            red[256 + t] = fmaxf(red[256 + t], red[256 + t + s]);
        }
        __syncthreads();
    }
    const float mx0 = red[0], mx1 = red[256];
    __syncthreads();
    const float e0 = expf(sc[t] - mx0);
    const float e1 = expf(sc[t + 256] - mx1);
    red[t] = e0; red[t + 256] = e1;
    __syncthreads();
    for (int s = 128; s > 0; s >>= 1) {
        if (t < s) { red[t] += red[t + s]; red[256 + t] += red[256 + t + s]; }
        __syncthreads();
    }
    sc[t] = e0 / red[0];
    sc[t + 256] = e1 / red[256];
    __syncthreads();

    const int c = cgp * 64 + (t & 63);
    const int jg = t >> 6;
    float a0 = 0.f, a1 = 0.f;
    for (int j = jg * 64; j < jg * 64 + 64; ++j) {
        const float cv = cap[((size_t)(b * 256 + j)) * 512 + c];
        a0 += sc[j] * cv;
        a1 += sc[256 + j] * cv;
    }
    red[t] = a0;
    __syncthreads();
    if (t < 64) {
        const float s0 = red[t] + red[t + 64] + red[t + 128] + red[t + 192];
        pbar[b * 1024 + cgp * 64 + t] = s0;
    }
    __syncthreads();
    red[t] = a1;
    __syncthreads();
    if (t < 64) {
        const float s1 = red[t] + red[t + 64] + red[t + 128] + red[t + 192];
        pbar[b * 1024 + 512 + cgp * 64 + t] = s1;
    }
}

// ---------------- x = pbar@Wv^T + bv, BN1, residual ----------------
__global__ __launch_bounds__(256)
void bnx_kernel(const float* __restrict__ pbar, const float* __restrict__ cap,
                const int* __restrict__ lengths,
                const float* __restrict__ Wv, const float* __restrict__ bv,
                const float* __restrict__ g1, const float* __restrict__ b1,
                const float* __restrict__ m1, const float* __restrict__ v1,
                float* __restrict__ xga)
{
    __shared__ float pb[1024];
    const int b = blockIdx.x;
    const int t = threadIdx.x;
    int r = lengths[b] - 1;
    if (r < 0) r = 0;
    if (r > 255) r = 255;
    const size_t base = ((size_t)b * 256 + r) * 512;
    pb[t] = pbar[b * 1024 + t];
    pb[t + 256] = pbar[b * 1024 + 256 + t];
    pb[t + 512] = pbar[b * 1024 + 512 + t];
    pb[t + 768] = pbar[b * 1024 + 768 + t];
    __syncthreads();
    float x0 = 0.f, x1 = 0.f;
    {
        const float4* w4 = (const float4*)(Wv + (size_t)t * 512);
        for (int k4 = 0; k4 < 128; ++k4) {
            float4 w = w4[k4];
            x0 += w.x * pb[k4 * 4 + 0] + w.y * pb[k4 * 4 + 1]
                + w.z * pb[k4 * 4 + 2] + w.w * pb[k4 * 4 + 3];
        }
        x0 += bv[t];
    }
    {
        const float4* w4 = (const float4*)(Wv + (size_t)(t + 256) * 512);
        for (int k4 = 0; k4 < 128; ++k4) {
            float4 w = w4[k4];
            x1 += w.x * pb[512 + k4 * 4 + 0] + w.y * pb[512 + k4 * 4 + 1]
                + w.z * pb[512 + k4 * 4 + 2] + w.w * pb[512 + k4 * 4 + 3];
        }
        x1 += bv[t + 256];
    }
    const int c0 = t, c1 = t + 256;
    const float s0 = g1[c0] / sqrtf(v1[c0] + 1e-5f);
    const float s1 = g1[c1] / sqrtf(v1[c1] + 1e-5f);
    xga[b * 512 + c0] = cap[base + c0] + (x0 - m1[c0]) * s0 + b1[c0];
    xga[b * 512 + c1] = cap[base + c1] + (x1 - m1[c1]) * s1 + b1[c1];
}

// ---------------- MLP strip GEMMs (weights read once) ----------------
__global__ __launch_bounds__(256)
void mlp1(const float* __restrict__ xga, const float* __restrict__ W,
          const float* __restrict__ bias, float* __restrict__ hid)
{
    __shared__ float xs[16 * 512];
    const int r0 = blockIdx.y * 16;
    const int c0 = blockIdx.x * 64;
    for (int i = threadIdx.x; i < 2048; i += 256)
        ((float4*)xs)[i] = ((const float4*)(xga + (size_t)r0 * 512))[i];
    __syncthreads();
    const int col = c0 + (threadIdx.x & 63);
    const int rg = (threadIdx.x >> 6) * 4;
    float acc[4] = {0.f, 0.f, 0.f, 0.f};
    const float4* w4 = (const float4*)(W + (size_t)col * 512);
    for (int k4 = 0; k4 < 128; ++k4) {
        float4 w = w4[k4];
#pragma unroll
        for (int rr = 0; rr < 4; ++rr) {
            float4 x = *(const float4*)&xs[(rg + rr) * 512 + k4 * 4];
            acc[rr] += w.x * x.x + w.y * x.y + w.z * x.z + w.w * x.w;
        }
    }
    const float bb = bias[col];
#pragma unroll
    for (int rr = 0; rr < 4; ++rr)
        hid[(size_t)(r0 + rg + rr) * 1024 + col] = fmaxf(acc[rr] + bb, 0.f);
}

__global__ __launch_bounds__(256)
void mlp2(const float* __restrict__ hid, const float* __restrict__ W,
          const float* __restrict__ bias, const float* __restrict__ xga,
          float* __restrict__ tex)
{
    __shared__ float xs[16 * 1024];
    const int r0 = blockIdx.y * 16;
    const int c0 = blockIdx.x * 64;
    for (int i = threadIdx.x; i < 4096; i += 256)
        ((float4*)xs)[i] = ((const float4*)(hid + (size_t)r0 * 1024))[i];
    __syncthreads();
    const int col = c0 + (threadIdx.x & 63);
    const int rg = (threadIdx.x >> 6) * 4;
    float acc[4] = {0.f, 0.f, 0.f, 0.f};
    const float4* w4 = (const float4*)(W + (size_t)col * 1024);
    for (int k4 = 0; k4 < 256; ++k4) {
        float4 w = w4[k4];
#pragma unroll
        for (int rr = 0; rr < 4; ++rr) {
            float4 x = *(const float4*)&xs[(rg + rr) * 1024 + k4 * 4];
            acc[rr] += w.x * x.x + w.y * x.y + w.z * x.z + w.w * x.w;
        }
    }
    const float bb = bias[col];
#pragma unroll
    for (int rr = 0; rr < 4; ++rr) {
        const int row = r0 + rg + rr;
        tex[(size_t)row * 512 + col] = acc[rr] + bb + xga[(size_t)row * 512 + col];
    }
}

__global__ __launch_bounds__(256)
void norm_out(const float* __restrict__ tex, float* __restrict__ out)
{
    __shared__ float red[256];
    const int b = blockIdx.x;
    const int t = threadIdx.x;
    const float a = tex[b * 512 + t];
    const float c = tex[b * 512 + 256 + t];
    red[t] = a * a + c * c;
    __syncthreads();
    for (int s = 128; s > 0; s >>= 1) {
        if (t < s) red[t] += red[t + s];
        __syncthreads();
    }
    const float inv = 1.f / (sqrtf(red[0]) + 1e-8f);
    out[b * 512 + t] = a * inv;
    out[b * 512 + 256 + t] = c * inv;
}

extern "C" void kernel_launch(void* const* d_in, const int* in_sizes, int n_in,
                              void* d_out, int out_size, void* d_ws, size_t ws_size,
                              hipStream_t stream)
{
    const float* cap = (const float*)d_in[0];
    const int* lengths = (const int*)d_in[1];
    const float* Wq  = (const float*)d_in[2];
    const float* Wk  = (const float*)d_in[3];
    const float* Wv  = (const float*)d_in[4];
    const float* bq  = (const float*)d_in[5];
    const float* bk  = (const float*)d_in[6];
    const float* bv  = (const float*)d_in[7];
    const float* Wfq = (const float*)d_in[8];
    const float* bfq = (const float*)d_in[9];
    const float* Wfk = (const float*)d_in[10];
    const float* bfk = (const float*)d_in[11];
    const float* Wfg = (const float*)d_in[12];
    const float* bfg = (const float*)d_in[13];
    const float* g1  = (const float*)d_in[14];
    const float* b1  = (const float*)d_in[15];
    const float* m1  = (const float*)d_in[16];
    const float* v1  = (const float*)d_in[17];
    const float* Wm1 = (const float*)d_in[30];
    const float* bm1 = (const float*)d_in[31];
    const float* Wm2 = (const float*)d_in[32];
    const float* bm2 = (const float*)d_in[33];
    float* out = (float*)d_out;

    char* w = (char*)d_ws;
    const size_t MB = 1024 * 1024;
    short* capHi = (short*)(w);                // 32MB  -> Ghi after G gemm
    short* capLo = (short*)(w + 32 * MB);      // 32MB  -> Glo
    short* KAhi  = (short*)(w + 64 * MB);      // 64MB  [32768,1024]: cols 0-511 K, 512-1023 A=Fq(Q)
    short* KAlo  = (short*)(w + 128 * MB);     // 64MB
    char* wp = w + 192 * MB;
    short* WBhi  = (short*)wp; wp += 1048576;  // [1024,512]: rows 0-511 Wk, 512-1023 Wa
    short* WBlo  = (short*)wp; wp += 1048576;
    short* WfkHi = (short*)wp; wp += 131072;
    short* WfkLo = (short*)wp; wp += 131072;
    short* Wfg2Hi = (short*)wp; wp += 131072;
    short* Wfg2Lo = (short*)wp; wp += 131072;
    float* ba     = (float*)wp; wp += 2048;
    float* qg     = (float*)wp; wp += 262144;
    float* scorep = (float*)wp; wp += 262144;   // [65536] = [b][j][h]
    float* pbar   = (float*)wp; wp += 524288;   // [128][2][512]
    float* xga    = (float*)wp; wp += 262144;
    float* hid    = (float*)wp; wp += 524288;
    float* tex    = (float*)wp; wp += 262144;
    short* Ghi = capHi;   // [65536, 256] == [32768, 512]
    short* Glo = capLo;

    // 1. splits: cap, Wk (-> WB rows 0-511), Wfk, Wfg2
    SplitArgs sa;
    sa.src[0] = cap;          sa.hi[0] = capHi;  sa.lo[0] = capLo;  sa.n4[0] = 4194304;
    sa.src[1] = Wk;           sa.hi[1] = WBhi;   sa.lo[1] = WBlo;   sa.n4[1] = 65536;
    sa.src[2] = Wfk;          sa.hi[2] = WfkHi;  sa.lo[2] = WfkLo;  sa.n4[2] = 16384;
    sa.src[3] = Wfg + 65536;  sa.hi[3] = Wfg2Hi; sa.lo[3] = Wfg2Lo; sa.n4[3] = 16384;
    split_multi<<<dim3(4096, 4), 256, 0, stream>>>(sa);

    // 2. composed Wa -> WB rows 512-1023, ba
    compose<<<dim3(512), 256, 0, stream>>>(Wq, bq, Wfq, bfq, WBhi, WBlo, ba);

    // 3. KA fused: 256^2-tile ring kernel
    gemm_ka256<<<dim3(4, 128), 512, 0, stream>>>(capHi, capLo, WBhi, WBlo, bk, ba, KAhi, KAlo);

    // 4. G = (K_h Wfk^T + bfk) * A  (reshaped ring)  -> overwrites cap splits
    gemm_rs<0><<<dim3(256), 512, 0, stream>>>(KAhi, KAlo, WfkHi, WfkLo, bfk,
                                              KAhi, KAlo, nullptr, nullptr, Ghi, Glo);

    // 5. qg at gathered rows (Q fp32 from cap)
    qg_kernel<<<dim3(256), 256, 0, stream>>>(cap, Ghi, Glo, Wq, bq, Wfg, bfg, lengths, qg);

    // 6. kg + fused scores (reshaped ring)
    gemm_rs<1><<<dim3(256), 512, 0, stream>>>(Ghi, Glo, Wfg2Hi, Wfg2Lo, bfg + 256,
                                              KAhi, KAlo, qg, scorep, nullptr, nullptr);

    // 7-8. softmax+pbar, BN/residual
    pbar_kernel<<<dim3(8, 128), 256, 0, stream>>>(scorep, cap, pbar);
    bnx_kernel<<<dim3(128), 256, 0, stream>>>(pbar, cap, lengths, Wv, bv, g1, b1, m1, v1, xga);

    // 9-11. MLP, norm
    mlp1<<<dim3(16, 8), 256, 0, stream>>>(xga, Wm1, bm1, hid);
    mlp2<<<dim3(8, 8), 256, 0, stream>>>(hid, Wm2, bm2, xga, tex);
    norm_out<<<dim3(128), 256, 0, stream>>>(tex, out);
}

// Round 10
// 320.618 us; speedup vs baseline: 1.7767x; 1.5390x over previous
//
#include <hip/hip_runtime.h>
#include <math.h>

// BS=128, L=256, D=512, H=2, DK=256.
// Conv branches dead (gather idx < 256). Split-bf16 MFMA GEMMs, all via the
// proven 2-phase __syncthreads-only kernel (no manual barriers/vmcnt).
// A = Fq(Q(x)) via composed weight; V GEMM removed via x=(p@cap)@Wv^T+bv.
// Gate-shielding: A, G, kg-gemm 1-pass bf16 (feed only sigmoid args);
// K 3-pass split (linear score path).

typedef short bf16x8 __attribute__((ext_vector_type(8)));
typedef float f32x4 __attribute__((ext_vector_type(4)));
typedef short short4v __attribute__((ext_vector_type(4)));

__device__ __forceinline__ short f2bf(float x) {
    union { float f; unsigned u; } c; c.f = x;
    unsigned r = c.u + 0x7FFFu + ((c.u >> 16) & 1u);
    return (short)(r >> 16);
}
__device__ __forceinline__ float bf2f(short h) {
    union { float f; unsigned u; } c; c.u = ((unsigned)(unsigned short)h) << 16;
    return c.f;
}
__device__ __forceinline__ void glds16(const void* g, void* l) {
    __builtin_amdgcn_global_load_lds(
        (const __attribute__((address_space(1))) void*)g,
        (__attribute__((address_space(3))) void*)l, 16, 0, 0);
}

// ---------------- split fp32 -> bf16 hi/lo ----------------
struct SplitArgs {
    const float* src[4];
    short* hi[4];
    short* lo[4];
    int n4[4];
};
__global__ __launch_bounds__(256) void split_multi(SplitArgs a)
{
    const int j = blockIdx.y;
    const float4* s = (const float4*)a.src[j];
    short* hi = a.hi[j];
    short* lo = a.lo[j];
    const int n4 = a.n4[j];
    for (int i = blockIdx.x * 256 + threadIdx.x; i < n4; i += gridDim.x * 256) {
        float4 x = s[i];
        short4v h, l;
        h.x = f2bf(x.x); l.x = f2bf(x.x - bf2f(h.x));
        h.y = f2bf(x.y); l.y = f2bf(x.y - bf2f(h.y));
        h.z = f2bf(x.z); l.z = f2bf(x.z - bf2f(h.z));
        h.w = f2bf(x.w); l.w = f2bf(x.w - bf2f(h.w));
        *(short4v*)&hi[i * 4] = h;
        *(short4v*)&lo[i * 4] = l;
    }
}

// ---------------- composed weight Wa = Wfq @ Wq_h (bf16), ba = Wfq@bq_h + bfq ----
__global__ __launch_bounds__(256)
void compose(const float* __restrict__ Wq, const float* __restrict__ bq,
             const float* __restrict__ Wfq, const float* __restrict__ bfq,
             short* __restrict__ WaHi, float* __restrict__ ba)
{
    __shared__ float fq[256];
    __shared__ float redc[256];
    const int op = blockIdx.x;          // 0..511: h = op>>8, o = op&255
    const int h = op >> 8, o = op & 255;
    const int t = threadIdx.x;
    fq[t] = Wfq[o * 256 + t];
    redc[t] = fq[t] * bq[h * 256 + t];
    __syncthreads();
    for (int s = 128; s > 0; s >>= 1) {
        if (t < s) redc[t] += redc[t + s];
        __syncthreads();
    }
    if (t == 0) ba[op] = redc[0] + bfq[o];
    float s0 = 0.f, s1 = 0.f;
    for (int d = 0; d < 256; ++d) {
        const float f = fq[d];
        const float* wr = Wq + (size_t)(h * 256 + d) * 512;
        s0 += f * wr[t];
        s1 += f * wr[t + 256];
    }
    const size_t ro = (size_t)op * 512;
    WaHi[ro + t] = f2bf(s0);
    WaHi[ro + 256 + t] = f2bf(s1);
}

// ---------------- 2-phase 128^2 GEMM, __syncthreads-only ----------------
// NSPLIT 3: virtual passes hi*hi + lo*hi + hi*lo (all staged per chunk).
// MODE 1: split write (C0,C1)     MODE 2: bf16 write (C0)
// MODE 3: bf16 write of (acc+bias)*E1
// MODE 4: score partials from sigmoid(acc+bias)*(E1+E2)*qg
template<int NSPLIT, int MODE>
__global__ __launch_bounds__(256, 2)
void gemm2p(const short* __restrict__ Ahi, const short* __restrict__ Alo,
            int lda, int aoff,
            const short* __restrict__ Bhi, const short* __restrict__ Blo, int ldb,
            const float* __restrict__ bias,
            const short* __restrict__ E1, const short* __restrict__ E2,
            int ldep, int eoff,
            const float* __restrict__ qg, float* __restrict__ scorep,
            short* __restrict__ C0, short* __restrict__ C1,
            int ldc, int coff, int K)
{
    constexpr int SLOT = (NSPLIT == 3) ? 16384 : 8192;
    __shared__ short lds[2][SLOT];
    __shared__ float sp[256];
    const int tid = threadIdx.x;
    const int bm = blockIdx.y * 128;
    const int bn = blockIdx.x * 128;
    const int z = blockIdx.z;
    const short* Ah = Ahi + (size_t)z * aoff;
    const short* Al = (NSPLIT == 3) ? (Alo + (size_t)z * aoff) : nullptr;

    const int lane = tid & 63;
    const int wr = (tid >> 7) & 1, wc = (tid >> 6) & 1;
    const int fr = lane & 15, kc = lane >> 4;
    const int r0 = tid >> 2;
    const int e0 = (((tid & 3) ^ ((r0 >> 1) & 3))) * 8;   // pre-swizzled source
    const int kce = (kc ^ ((fr >> 1) & 3)) * 8;           // read-side swizzle

    auto stage = [&](int ph, int k0) {
        short* b = lds[ph];
        glds16(Ah + (size_t)(bm + r0) * lda + k0 + e0,       b + tid * 8);
        glds16(Ah + (size_t)(bm + r0 + 64) * lda + k0 + e0,  b + (tid + 256) * 8);
        glds16(Bhi + (size_t)(bn + r0) * ldb + k0 + e0,      b + 4096 + tid * 8);
        glds16(Bhi + (size_t)(bn + r0 + 64) * ldb + k0 + e0, b + 4096 + (tid + 256) * 8);
        if constexpr (NSPLIT == 3) {
            glds16(Al + (size_t)(bm + r0) * lda + k0 + e0,       b + 8192 + tid * 8);
            glds16(Al + (size_t)(bm + r0 + 64) * lda + k0 + e0,  b + 8192 + (tid + 256) * 8);
            glds16(Blo + (size_t)(bn + r0) * ldb + k0 + e0,      b + 12288 + tid * 8);
            glds16(Blo + (size_t)(bn + r0 + 64) * ldb + k0 + e0, b + 12288 + (tid + 256) * 8);
        }
    };

    f32x4 acc[4][4];
#pragma unroll
    for (int i = 0; i < 4; ++i)
#pragma unroll
        for (int j = 0; j < 4; ++j) acc[i][j] = (f32x4){0.f, 0.f, 0.f, 0.f};

    stage(0, 0);
    __syncthreads();
    const int NS = K / 32;
    for (int s = 0; s < NS; ++s) {
        if (s + 1 < NS) stage((s + 1) & 1, (s + 1) * 32);
        const short* b = lds[s & 1];
        bf16x8 ah[4], bh[4];
#pragma unroll
        for (int i = 0; i < 4; ++i)
            ah[i] = *(const bf16x8*)&b[(wr * 64 + i * 16 + fr) * 32 + kce];
#pragma unroll
        for (int i = 0; i < 4; ++i)
            bh[i] = *(const bf16x8*)&b[4096 + (wc * 64 + i * 16 + fr) * 32 + kce];
#pragma unroll
        for (int mi = 0; mi < 4; ++mi)
#pragma unroll
            for (int ni = 0; ni < 4; ++ni)
                acc[mi][ni] = __builtin_amdgcn_mfma_f32_16x16x32_bf16(ah[mi], bh[ni], acc[mi][ni], 0, 0, 0);
        if constexpr (NSPLIT == 3) {
            bf16x8 al[4], bl[4];
#pragma unroll
            for (int i = 0; i < 4; ++i)
                al[i] = *(const bf16x8*)&b[8192 + (wr * 64 + i * 16 + fr) * 32 + kce];
#pragma unroll
            for (int mi = 0; mi < 4; ++mi)
#pragma unroll
                for (int ni = 0; ni < 4; ++ni)
                    acc[mi][ni] = __builtin_amdgcn_mfma_f32_16x16x32_bf16(al[mi], bh[ni], acc[mi][ni], 0, 0, 0);
#pragma unroll
            for (int i = 0; i < 4; ++i)
                bl[i] = *(const bf16x8*)&b[12288 + (wc * 64 + i * 16 + fr) * 32 + kce];
#pragma unroll
            for (int mi = 0; mi < 4; ++mi)
#pragma unroll
                for (int ni = 0; ni < 4; ++ni)
                    acc[mi][ni] = __builtin_amdgcn_mfma_f32_16x16x32_bf16(ah[mi], bl[ni], acc[mi][ni], 0, 0, 0);
        }
        __syncthreads();
    }

    float qgv[4];
    float pt[4][4];
    if (MODE == 4) {
        const int b = bm >> 8;
#pragma unroll
        for (int ni = 0; ni < 4; ++ni)
            qgv[ni] = qg[b * 512 + z * 256 + bn + wc * 64 + ni * 16 + fr];
#pragma unroll
        for (int mi = 0; mi < 4; ++mi)
#pragma unroll
            for (int r = 0; r < 4; ++r) pt[mi][r] = 0.f;
    }

#pragma unroll
    for (int mi = 0; mi < 4; ++mi) {
#pragma unroll
        for (int ni = 0; ni < 4; ++ni) {
#pragma unroll
            for (int r = 0; r < 4; ++r) {
                const int row = bm + wr * 64 + mi * 16 + kc * 4 + r;
                const int col = bn + wc * 64 + ni * 16 + fr;
                const float v = acc[mi][ni][r] + bias[col];
                if (MODE == 1) {
                    const size_t off = (size_t)row * ldc + (size_t)z * coff + col;
                    short h = f2bf(v);
                    C0[off] = h;
                    C1[off] = f2bf(v - bf2f(h));
                } else if (MODE == 2) {
                    C0[(size_t)row * ldc + (size_t)z * coff + col] = f2bf(v);
                } else if (MODE == 3) {
                    const size_t eoffs = (size_t)row * ldep + (size_t)z * eoff + col;
                    const float e = bf2f(E1[eoffs]);
                    C0[(size_t)row * ldc + (size_t)z * coff + col] = f2bf(v * e);
                } else if (MODE == 4) {
                    const size_t eoffs = (size_t)row * ldep + (size_t)z * eoff + col;
                    const float e = bf2f(E1[eoffs]) + bf2f(E2[eoffs]);
                    const float kgv = e / (1.f + expf(-v));
                    pt[mi][r] += kgv * qgv[ni];
                }
            }
        }
    }

    if (MODE == 4) {
#pragma unroll
        for (int mi = 0; mi < 4; ++mi) {
#pragma unroll
            for (int r = 0; r < 4; ++r) {
                float p = pt[mi][r];
                p += __shfl_xor(p, 1);
                p += __shfl_xor(p, 2);
                p += __shfl_xor(p, 4);
                p += __shfl_xor(p, 8);
                if (fr == 0) {
                    const int row_local = wr * 64 + mi * 16 + kc * 4 + r;
                    sp[row_local * 2 + wc] = p;
                }
            }
        }
        __syncthreads();
        if (tid < 128) {
            const int row = bm + tid;
            const float s = sp[tid * 2] + sp[tid * 2 + 1];
            const int b = row >> 8, j = row & 255;
            scorep[((size_t)(b * 2 + z) * 256 + j) * 2 + blockIdx.x] = s;
        }
    }
}

// ---------------- qg at gathered rows: Q fp32-exact from cap ----------------
__global__ __launch_bounds__(256)
void qg_kernel(const float* __restrict__ cap,
               const short* __restrict__ Ghi,
               const float* __restrict__ Wq, const float* __restrict__ bq,
               const float* __restrict__ Wfg, const float* __restrict__ bfg,
               const int* __restrict__ lengths, float* __restrict__ qg)
{
    __shared__ float cr[512];
    __shared__ float gs[256];
    const int b = blockIdx.x >> 1, h = blockIdx.x & 1;
    const int t = threadIdx.x;
    int r = lengths[b] - 1;
    if (r < 0) r = 0;
    if (r > 255) r = 255;
    const size_t base = ((size_t)b * 256 + r) * 512;
    cr[t] = cap[base + t];
    cr[t + 256] = cap[base + 256 + t];
    gs[t] = bf2f(Ghi[base + h * 256 + t]);
    __syncthreads();
    const float4* wq4 = (const float4*)(Wq + (size_t)(h * 256 + t) * 512);
    float q = 0.f;
    for (int k4 = 0; k4 < 128; ++k4) {
        float4 w = wq4[k4];
        q += w.x * cr[k4 * 4 + 0] + w.y * cr[k4 * 4 + 1]
           + w.z * cr[k4 * 4 + 2] + w.w * cr[k4 * 4 + 3];
    }
    q += bq[h * 256 + t];
    const float4* w4 = (const float4*)(Wfg + (size_t)t * 256);
    float a = 0.f;
    for (int k4 = 0; k4 < 64; ++k4) {
        float4 w = w4[k4];
        a += w.x * gs[k4 * 4 + 0] + w.y * gs[k4 * 4 + 1]
           + w.z * gs[k4 * 4 + 2] + w.w * gs[k4 * 4 + 3];
    }
    a += bfg[t];
    qg[b * 512 + h * 256 + t] = q / (1.f + expf(-a));
}

// ---------------- softmax (per sample, both heads) ----------------
__global__ __launch_bounds__(256)
void softmax_p(const float* __restrict__ scorep, float* __restrict__ pn)
{
    __shared__ float sc[512], red[512];
    const int b = blockIdx.x;
    const int t = threadIdx.x;
#pragma unroll
    for (int i = 0; i < 2; ++i) {
        const int o = t + i * 256;
        const int h = o >> 8, j = o & 255;
        const size_t si = ((size_t)(b * 2 + h) * 256 + j) * 2;
        sc[o] = floorf((scorep[si] + scorep[si + 1]) * 0.0625f);
    }
    __syncthreads();
    red[t] = sc[t]; red[t + 256] = sc[t + 256];
    __syncthreads();
    for (int s = 128; s > 0; s >>= 1) {
        if (t < s) {
            red[t] = fmaxf(red[t], red[t + s]);
            red[256 + t] = fmaxf(red[256 + t], red[256 + t + s]);
        }
        __syncthreads();
    }
    const float mx0 = red[0], mx1 = red[256];
    __syncthreads();
    const float e0 = expf(sc[t] - mx0);
    const float e1 = expf(sc[t + 256] - mx1);
    red[t] = e0; red[t + 256] = e1;
    __syncthreads();
    for (int s = 128; s > 0; s >>= 1) {
        if (t < s) { red[t] += red[t + s]; red[256 + t] += red[256 + t + s]; }
        __syncthreads();
    }
    pn[b * 512 + t] = e0 / red[0];
    pn[b * 512 + 256 + t] = e1 / red[256];
}

// ---------------- pbar[b][h][c] = sum_j p[h][j]*cap[b,j,c], parallel ----------------
__global__ __launch_bounds__(256)
void pbar_kernel(const float* __restrict__ pn, const float* __restrict__ cap,
                 float* __restrict__ pbar)
{
    __shared__ float p0s[256], p1s[256], r0[256], r1[256];
    const int b = blockIdx.y, cg = blockIdx.x;
    const int t = threadIdx.x;
    p0s[t] = pn[b * 512 + t];
    p1s[t] = pn[b * 512 + 256 + t];
    __syncthreads();
    const int c = cg * 64 + (t & 63);
    const int jg = t >> 6;
    float a0 = 0.f, a1 = 0.f;
    for (int j = jg * 64; j < jg * 64 + 64; ++j) {
        const float cv = cap[((size_t)(b * 256 + j)) * 512 + c];
        a0 += p0s[j] * cv;
        a1 += p1s[j] * cv;
    }
    r0[t] = a0; r1[t] = a1;
    __syncthreads();
    if (t < 64) {
        const float s0 = r0[t] + r0[t + 64] + r0[t + 128] + r0[t + 192];
        const float s1 = r1[t] + r1[t + 64] + r1[t + 128] + r1[t + 192];
        pbar[b * 1024 + cg * 64 + t] = s0;
        pbar[b * 1024 + 512 + cg * 64 + t] = s1;
    }
}

// ---------------- x = pbar@Wv^T + bv, BN1, residual ----------------
__global__ __launch_bounds__(256)
void bnx_kernel(const float* __restrict__ pbar, const float* __restrict__ cap,
                const int* __restrict__ lengths,
                const float* __restrict__ Wv, const float* __restrict__ bv,
                const float* __restrict__ g1, const float* __restrict__ b1,
                const float* __restrict__ m1, const float* __restrict__ v1,
                float* __restrict__ xga)
{
    __shared__ float pb[1024];
    const int b = blockIdx.x;
    const int t = threadIdx.x;
    int r = lengths[b] - 1;
    if (r < 0) r = 0;
    if (r > 255) r = 255;
    const size_t base = ((size_t)b * 256 + r) * 512;
    pb[t] = pbar[b * 1024 + t];
    pb[t + 256] = pbar[b * 1024 + 256 + t];
    pb[t + 512] = pbar[b * 1024 + 512 + t];
    pb[t + 768] = pbar[b * 1024 + 768 + t];
    __syncthreads();
    float x0 = 0.f, x1 = 0.f;
    {
        const float4* w4 = (const float4*)(Wv + (size_t)t * 512);
        for (int k4 = 0; k4 < 128; ++k4) {
            float4 w = w4[k4];
            x0 += w.x * pb[k4 * 4 + 0] + w.y * pb[k4 * 4 + 1]
                + w.z * pb[k4 * 4 + 2] + w.w * pb[k4 * 4 + 3];
        }
        x0 += bv[t];
    }
    {
        const float4* w4 = (const float4*)(Wv + (size_t)(t + 256) * 512);
        for (int k4 = 0; k4 < 128; ++k4) {
            float4 w = w4[k4];
            x1 += w.x * pb[512 + k4 * 4 + 0] + w.y * pb[512 + k4 * 4 + 1]
                + w.z * pb[512 + k4 * 4 + 2] + w.w * pb[512 + k4 * 4 + 3];
        }
        x1 += bv[t + 256];
    }
    const int c0 = t, c1 = t + 256;
    const float s0 = g1[c0] / sqrtf(v1[c0] + 1e-5f);
    const float s1 = g1[c1] / sqrtf(v1[c1] + 1e-5f);
    xga[b * 512 + c0] = cap[base + c0] + (x0 - m1[c0]) * s0 + b1[c0];
    xga[b * 512 + c1] = cap[base + c1] + (x1 - m1[c1]) * s1 + b1[c1];
}

// ---------------- MLP strip GEMMs (weights read once) ----------------
__global__ __launch_bounds__(256)
void mlp1(const float* __restrict__ xga, const float* __restrict__ W,
          const float* __restrict__ bias, float* __restrict__ hid)
{
    __shared__ float xs[16 * 512];
    const int r0 = blockIdx.y * 16;
    const int c0 = blockIdx.x * 64;
    for (int i = threadIdx.x; i < 2048; i += 256)
        ((float4*)xs)[i] = ((const float4*)(xga + (size_t)r0 * 512))[i];
    __syncthreads();
    const int col = c0 + (threadIdx.x & 63);
    const int rg = (threadIdx.x >> 6) * 4;
    float acc[4] = {0.f, 0.f, 0.f, 0.f};
    const float4* w4 = (const float4*)(W + (size_t)col * 512);
    for (int k4 = 0; k4 < 128; ++k4) {
        float4 w = w4[k4];
#pragma unroll
        for (int rr = 0; rr < 4; ++rr) {
            float4 x = *(const float4*)&xs[(rg + rr) * 512 + k4 * 4];
            acc[rr] += w.x * x.x + w.y * x.y + w.z * x.z + w.w * x.w;
        }
    }
    const float bb = bias[col];
#pragma unroll
    for (int rr = 0; rr < 4; ++rr)
        hid[(size_t)(r0 + rg + rr) * 1024 + col] = fmaxf(acc[rr] + bb, 0.f);
}

__global__ __launch_bounds__(256)
void mlp2(const float* __restrict__ hid, const float* __restrict__ W,
          const float* __restrict__ bias, const float* __restrict__ xga,
          float* __restrict__ tex)
{
    __shared__ float xs[16 * 1024];
    const int r0 = blockIdx.y * 16;
    const int c0 = blockIdx.x * 64;
    for (int i = threadIdx.x; i < 4096; i += 256)
        ((float4*)xs)[i] = ((const float4*)(hid + (size_t)r0 * 1024))[i];
    __syncthreads();
    const int col = c0 + (threadIdx.x & 63);
    const int rg = (threadIdx.x >> 6) * 4;
    float acc[4] = {0.f, 0.f, 0.f, 0.f};
    const float4* w4 = (const float4*)(W + (size_t)col * 1024);
    for (int k4 = 0; k4 < 256; ++k4) {
        float4 w = w4[k4];
#pragma unroll
        for (int rr = 0; rr < 4; ++rr) {
            float4 x = *(const float4*)&xs[(rg + rr) * 1024 + k4 * 4];
            acc[rr] += w.x * x.x + w.y * x.y + w.z * x.z + w.w * x.w;
        }
    }
    const float bb = bias[col];
#pragma unroll
    for (int rr = 0; rr < 4; ++rr) {
        const int row = r0 + rg + rr;
        tex[(size_t)row * 512 + col] = acc[rr] + bb + xga[(size_t)row * 512 + col];
    }
}

__global__ __launch_bounds__(256)
void norm_out(const float* __restrict__ tex, float* __restrict__ out)
{
    __shared__ float red[256];
    const int b = blockIdx.x;
    const int t = threadIdx.x;
    const float a = tex[b * 512 + t];
    const float c = tex[b * 512 + 256 + t];
    red[t] = a * a + c * c;
    __syncthreads();
    for (int s = 128; s > 0; s >>= 1) {
        if (t < s) red[t] += red[t + s];
        __syncthreads();
    }
    const float inv = 1.f / (sqrtf(red[0]) + 1e-8f);
    out[b * 512 + t] = a * inv;
    out[b * 512 + 256 + t] = c * inv;
}

extern "C" void kernel_launch(void* const* d_in, const int* in_sizes, int n_in,
                              void* d_out, int out_size, void* d_ws, size_t ws_size,
                              hipStream_t stream)
{
    const float* cap = (const float*)d_in[0];
    const int* lengths = (const int*)d_in[1];
    const float* Wq  = (const float*)d_in[2];
    const float* Wk  = (const float*)d_in[3];
    const float* Wv  = (const float*)d_in[4];
    const float* bq  = (const float*)d_in[5];
    const float* bk  = (const float*)d_in[6];
    const float* bv  = (const float*)d_in[7];
    const float* Wfq = (const float*)d_in[8];
    const float* bfq = (const float*)d_in[9];
    const float* Wfk = (const float*)d_in[10];
    const float* bfk = (const float*)d_in[11];
    const float* Wfg = (const float*)d_in[12];
    const float* bfg = (const float*)d_in[13];
    const float* g1  = (const float*)d_in[14];
    const float* b1  = (const float*)d_in[15];
    const float* m1  = (const float*)d_in[16];
    const float* v1  = (const float*)d_in[17];
    const float* Wm1 = (const float*)d_in[30];
    const float* bm1 = (const float*)d_in[31];
    const float* Wm2 = (const float*)d_in[32];
    const float* bm2 = (const float*)d_in[33];
    float* out = (float*)d_out;

    char* w = (char*)d_ws;
    const size_t MB = 1024 * 1024;
    short* capHi = (short*)(w);                // 32MB  -> Ghi after G gemm
    short* capLo = (short*)(w + 32 * MB);      // 32MB
    short* KAhi  = (short*)(w + 64 * MB);      // 64MB  [32768,1024]: 0-511 K, 512-1023 A
    short* KAlo  = (short*)(w + 128 * MB);     // 64MB  (only K-half written/used)
    char* wp = w + 192 * MB;
    short* WkHi  = (short*)wp; wp += 524288;   // [512,512]
    short* WkLo  = (short*)wp; wp += 524288;
    short* WaHi  = (short*)wp; wp += 524288;   // [512,512] composed
    short* WfkHi = (short*)wp; wp += 131072;
    short* WfkLo = (short*)wp; wp += 131072;   // written, unused
    short* Wfg2Hi = (short*)wp; wp += 131072;
    short* Wfg2Lo = (short*)wp; wp += 131072;  // written, unused
    float* ba     = (float*)wp; wp += 2048;
    float* qg     = (float*)wp; wp += 262144;
    float* scorep = (float*)wp; wp += 524288;   // [128][2][256][2]
    float* pn     = (float*)wp; wp += 262144;
    float* pbar   = (float*)wp; wp += 524288;
    float* xga    = (float*)wp; wp += 262144;
    float* hid    = (float*)wp; wp += 524288;
    float* tex    = (float*)wp; wp += 262144;
    short* Ghi = capHi;   // [32768, 512] bf16

    // 1. splits: cap, Wk, Wfk, Wfg2
    SplitArgs sa;
    sa.src[0] = cap;          sa.hi[0] = capHi;  sa.lo[0] = capLo;  sa.n4[0] = 4194304;
    sa.src[1] = Wk;           sa.hi[1] = WkHi;   sa.lo[1] = WkLo;   sa.n4[1] = 65536;
    sa.src[2] = Wfk;          sa.hi[2] = WfkHi;  sa.lo[2] = WfkLo;  sa.n4[2] = 16384;
    sa.src[3] = Wfg + 65536;  sa.hi[3] = Wfg2Hi; sa.lo[3] = Wfg2Lo; sa.n4[3] = 16384;
    split_multi<<<dim3(4096, 4), 256, 0, stream>>>(sa);

    // 2. composed Wa (bf16), ba
    compose<<<dim3(512), 256, 0, stream>>>(Wq, bq, Wfq, bfq, WaHi, ba);

    // 3. K projection: 3-pass split -> KA cols 0-511
    gemm2p<3, 1><<<dim3(4, 256, 1), 256, 0, stream>>>(
        capHi, capLo, 512, 0, WkHi, WkLo, 512, bk,
        nullptr, nullptr, 0, 0, nullptr, nullptr,
        KAhi, KAlo, 1024, 0, 512);

    // 4. A = Fq(Q): 1-pass bf16 -> KA cols 512-1023
    gemm2p<1, 2><<<dim3(4, 256, 1), 256, 0, stream>>>(
        capHi, nullptr, 512, 0, WaHi, nullptr, 512, ba,
        nullptr, nullptr, 0, 0, nullptr, nullptr,
        KAhi + 512, nullptr, 1024, 0, 512);

    // 5. G = (K_h Wfk^T + bfk) * A : 1-pass bf16 -> overwrites capHi
    gemm2p<1, 3><<<dim3(2, 256, 2), 256, 0, stream>>>(
        KAhi, nullptr, 1024, 256, WfkHi, nullptr, 256, bfk,
        KAhi + 512, nullptr, 1024, 256, nullptr, nullptr,
        Ghi, nullptr, 512, 256, 256);

    // 6. qg at gathered rows (Q fp32 from cap)
    qg_kernel<<<dim3(256), 256, 0, stream>>>(cap, Ghi, Wq, bq, Wfg, bfg, lengths, qg);

    // 7. kg gemm + fused score partials (1-pass gemm; K read split)
    gemm2p<1, 4><<<dim3(2, 256, 2), 256, 0, stream>>>(
        Ghi, nullptr, 512, 256, Wfg2Hi, nullptr, 256, bfg + 256,
        KAhi, KAlo, 1024, 256, qg, scorep,
        nullptr, nullptr, 0, 0, 256);

    // 8-10. softmax, parallel pbar, BN/residual
    softmax_p<<<dim3(128), 256, 0, stream>>>(scorep, pn);
    pbar_kernel<<<dim3(8, 128), 256, 0, stream>>>(pn, cap, pbar);
    bnx_kernel<<<dim3(128), 256, 0, stream>>>(pbar, cap, lengths, Wv, bv, g1, b1, m1, v1, xga);

    // 11-13. MLP, norm
    mlp1<<<dim3(16, 8), 256, 0, stream>>>(xga, Wm1, bm1, hid);
    mlp2<<<dim3(8, 8), 256, 0, stream>>>(hid, Wm2, bm2, xga, tex);
    norm_out<<<dim3(128), 256, 0, stream>>>(tex, out);
}